// Round 2
// baseline (1323.086 us; speedup 1.0000x reference)
//
#include <hip/hip_runtime.h>
#include <hip/hip_bf16.h>
#include <math.h>

#define BB 4096
#define TT 200
#define EE 64

// ws float layout:
//  [0,5120)          WkC = W1[64:128]-W1[128:192]   (64x80)
//  [5120,10240)      WqC = W1[0:64]+W1[128:192]     (64x80)
//  [10240,337920)    qW  = targets@WqC + b1         (B x 80)
//  [337920,1157120)  logits [T][B]
//  [1157120,1976320) scores [T][B]

__device__ __forceinline__ float lane_bcast(float v, int l) {
    return __int_as_float(__builtin_amdgcn_readlane(__float_as_int(v), l));
}

__global__ __launch_bounds__(256) void prep_kernel(const float* __restrict__ W1,
                                                   float* __restrict__ ws) {
    int idx = blockIdx.x * 256 + threadIdx.x;   // i*80+j, i<64
    if (idx >= 64 * 80) return;
    float wa = W1[idx];
    float wb = W1[64 * 80 + idx];
    float wc = W1[128 * 80 + idx];
    ws[idx]        = wb - wc;   // WkC
    ws[5120 + idx] = wa + wc;   // WqC
}

__global__ __launch_bounds__(256) void qw_kernel(const float* __restrict__ targets,
                                                 const float* __restrict__ b1,
                                                 const float* __restrict__ ws,
                                                 float* __restrict__ qW) {
    int idx = blockIdx.x * 256 + threadIdx.x;   // b*80+j
    int b = idx / 80;
    int j = idx - b * 80;
    const float* q  = targets + (size_t)b * 64;
    const float* Wq = ws + 5120;
    float s = b1[j];
#pragma unroll
    for (int i = 0; i < 64; i++) s = fmaf(q[i], Wq[i * 80 + j], s);
    qW[idx] = s;
}

// one thread per (b,t): logit via restructured MLP.
// Weight reads use wave-uniform addresses -> scalar loads (SALU pipe),
// FMAs take the weight as the single allowed SGPR operand.
__global__ __launch_bounds__(256) void mlp_kernel(
    const float* __restrict__ gru, const float* __restrict__ targets,
    const float* __restrict__ W1, const float* __restrict__ W2,
    const float* __restrict__ b2, const float* __restrict__ Wf,
    const float* __restrict__ bf, const float* __restrict__ ws,
    float* __restrict__ logits) {
    const float4* Wk = (const float4*)ws;               // WkC, 64x20 quads
    const float4* Wp = (const float4*)(W1 + 192 * 80);  // last 64 rows of W1

    int idx = blockIdx.x * 256 + threadIdx.x;   // exactly B*T threads
    int b = idx / 200;
    int t = idx - b * 200;
    const float4* kp  = (const float4*)(gru + ((size_t)b * 200 + t) * 64);
    const float4* qp  = (const float4*)(targets + (size_t)b * 64);
    const float4* qWv = (const float4*)(ws + 10240 + (size_t)b * 80);

    float4 h1[20];
#pragma unroll
    for (int j = 0; j < 20; j++) h1[j] = qWv[j];

    for (int i4 = 0; i4 < 16; i4++) {
        float4 kv = kp[i4];
        float4 qv = qp[i4];
        float kk[4] = {kv.x, kv.y, kv.z, kv.w};
        float pp[4] = {qv.x * kv.x, qv.y * kv.y, qv.z * kv.z, qv.w * kv.w};
#pragma unroll
        for (int u = 0; u < 4; u++) {
            const float4* wk = Wk + (i4 * 4 + u) * 20;   // uniform -> s_load
            const float4* wp = Wp + (i4 * 4 + u) * 20;   // uniform -> s_load
            float ki = kk[u], pi = pp[u];
#pragma unroll
            for (int j = 0; j < 20; j++) {
                float4 a = wk[j], c = wp[j];
                h1[j].x = fmaf(ki, a.x, fmaf(pi, c.x, h1[j].x));
                h1[j].y = fmaf(ki, a.y, fmaf(pi, c.y, h1[j].y));
                h1[j].z = fmaf(ki, a.z, fmaf(pi, c.z, h1[j].z));
                h1[j].w = fmaf(ki, a.w, fmaf(pi, c.w, h1[j].w));
            }
        }
    }
    // layer 2: 80 -> 40
    float4 h2[10];
    const float4* b2v = (const float4*)b2;
    const float4* W2v = (const float4*)W2;   // [80][10 quads]
#pragma unroll
    for (int j = 0; j < 10; j++) h2[j] = b2v[j];
#pragma unroll
    for (int iq = 0; iq < 20; iq++) {
        float4 hv = h1[iq];
        float hs[4] = {hv.x, hv.y, hv.z, hv.w};
#pragma unroll
        for (int u = 0; u < 4; u++) {
            float v = hs[u];
            const float4* wr = W2v + (iq * 4 + u) * 10;  // uniform -> s_load
#pragma unroll
            for (int j = 0; j < 10; j++) {
                float4 w = wr[j];
                h2[j].x = fmaf(v, w.x, h2[j].x);
                h2[j].y = fmaf(v, w.y, h2[j].y);
                h2[j].z = fmaf(v, w.z, h2[j].z);
                h2[j].w = fmaf(v, w.w, h2[j].w);
            }
        }
    }
    // final: 40 -> 1
    const float4* Wfv = (const float4*)Wf;
    float lg = bf[0];
#pragma unroll
    for (int j = 0; j < 10; j++) {
        float4 w = Wfv[j];
        lg = fmaf(h2[j].x, w.x, lg);
        lg = fmaf(h2[j].y, w.y, lg);
        lg = fmaf(h2[j].z, w.z, lg);
        lg = fmaf(h2[j].w, w.w, lg);
    }
    if (lg == 0.0f) lg = -INFINITY;
    logits[(size_t)t * BB + b] = lg;
}

// softmax over batch dim for each t
__global__ __launch_bounds__(256) void softmax_kernel(const float* __restrict__ logits,
                                                      float* __restrict__ scores) {
    int t = blockIdx.x;
    int tid = threadIdx.x;
    const float* L = logits + (size_t)t * BB;
    float v[16];
#pragma unroll
    for (int i = 0; i < 16; i++) {
        float x = L[tid + i * 256];
        v[i] = (x == 0.0f) ? -INFINITY : x;
    }
    float m = v[0];
#pragma unroll
    for (int i = 1; i < 16; i++) m = fmaxf(m, v[i]);
#pragma unroll
    for (int off = 32; off; off >>= 1) m = fmaxf(m, __shfl_xor(m, off));
    __shared__ float sm[4];
    __shared__ float ss[4];
    int wid = tid >> 6;
    if ((tid & 63) == 0) sm[wid] = m;
    __syncthreads();
    m = fmaxf(fmaxf(sm[0], sm[1]), fmaxf(sm[2], sm[3]));
    float e[16];
    float s = 0.0f;
#pragma unroll
    for (int i = 0; i < 16; i++) {
        e[i] = __expf(v[i] - m);
        s += e[i];
    }
#pragma unroll
    for (int off = 32; off; off >>= 1) s += __shfl_xor(s, off);
    if ((tid & 63) == 0) ss[wid] = s;
    __syncthreads();
    s = ss[0] + ss[1] + ss[2] + ss[3];
    float inv = 1.0f / s;
    float* S = scores + (size_t)t * BB;
#pragma unroll
    for (int i = 0; i < 16; i++) S[tid + i * 256] = e[i] * inv;
}

// AUGRU: one wave per batch row, lane j owns h[j] and the j-th columns of Wc.
// x-part of the candidate matvec uses wave-uniform scalar loads (SGPR operand);
// h-part broadcasts h via readlane; r (per-b scalar) is factored out of the
// matvec: sum_k (h[k]*r)*Wc2[k][j] == r * sum_k h[k]*Wc2[k][j].
__global__ __launch_bounds__(256, 3) void augru_kernel(
    const float* __restrict__ gru, const float* __restrict__ scores,
    const float* __restrict__ Wu, const float* __restrict__ bu,
    const float* __restrict__ Wr, const float* __restrict__ br,
    const float* __restrict__ Wc, const float* __restrict__ bc,
    float* __restrict__ out) {
    int lane = threadIdx.x & 63;
    int wid  = threadIdx.x >> 6;
    int b = __builtin_amdgcn_readfirstlane(blockIdx.x * 4 + wid);  // wave-uniform

    float wc1[64], wc2[64];
#pragma unroll
    for (int k = 0; k < 64; k++) {
        wc1[k] = Wc[k * 64 + lane];          // xi part, column `lane`
        wc2[k] = Wc[(64 + k) * 64 + lane];   // h*r part
    }
    float wu1l = Wu[lane], wu2l = Wu[64 + lane];
    float wr1l = Wr[lane], wr2l = Wr[64 + lane];
    float bcl = bc[lane];
    float sbu = bu[0], sbr = br[0];

    const float* xrow = gru + (size_t)b * TT * 64;   // wave-uniform base
    float h = 0.0f;
    for (int t = 0; t < TT; t++) {
        float xl = xrow[lane];                        // per-lane x (gate partial)
        float sc = scores[(size_t)t * BB + b];        // uniform -> s_load
        // gate partials + butterfly reduce (both gates together)
        float pu = fmaf(xl, wu1l, h * wu2l);
        float pr = fmaf(xl, wr1l, h * wr2l);
#pragma unroll
        for (int off = 32; off; off >>= 1) {
            pu += __shfl_xor(pu, off);
            pr += __shfl_xor(pr, off);
        }
        float u = sc / (1.0f + __expf(-(pu + sbu)));
        float r = 1.0f / (1.0f + __expf(-(pr + sbr)));
        // candidate matvec: x-part via uniform scalar loads, h-part via readlane
        float ax0 = bcl, ax1 = 0.0f, ax2 = 0.0f, ax3 = 0.0f;
        float ah0 = 0.0f, ah1 = 0.0f, ah2 = 0.0f, ah3 = 0.0f;
#pragma unroll
        for (int k = 0; k < 16; k++) {
            float x0 = xrow[4 * k + 0];   // uniform -> s_load
            float x1 = xrow[4 * k + 1];
            float x2 = xrow[4 * k + 2];
            float x3 = xrow[4 * k + 3];
            ax0 = fmaf(x0, wc1[4 * k + 0], ax0);
            ax1 = fmaf(x1, wc1[4 * k + 1], ax1);
            ax2 = fmaf(x2, wc1[4 * k + 2], ax2);
            ax3 = fmaf(x3, wc1[4 * k + 3], ax3);
            float h0 = lane_bcast(h, 4 * k + 0);
            float h1 = lane_bcast(h, 4 * k + 1);
            float h2 = lane_bcast(h, 4 * k + 2);
            float h3 = lane_bcast(h, 4 * k + 3);
            ah0 = fmaf(h0, wc2[4 * k + 0], ah0);
            ah1 = fmaf(h1, wc2[4 * k + 1], ah1);
            ah2 = fmaf(h2, wc2[4 * k + 2], ah2);
            ah3 = fmaf(h3, wc2[4 * k + 3], ah3);
        }
        float arg = ((ax0 + ax1) + (ax2 + ax3)) + r * ((ah0 + ah1) + (ah2 + ah3));
        float ex = __expf(2.0f * arg);                // tanh
        float th = 1.0f - 2.0f / (ex + 1.0f);
        h = fmaf(u, th - h, h);
        xrow += 64;
    }
    out[(size_t)b * 64 + lane] = h;
}

extern "C" void kernel_launch(void* const* d_in, const int* in_sizes, int n_in,
                              void* d_out, int out_size, void* d_ws, size_t ws_size,
                              hipStream_t stream) {
    const float* gru     = (const float*)d_in[0];
    const float* targets = (const float*)d_in[1];
    const float* W1 = (const float*)d_in[2];
    const float* b1 = (const float*)d_in[3];
    const float* W2 = (const float*)d_in[4];
    const float* b2 = (const float*)d_in[5];
    const float* Wf = (const float*)d_in[6];
    const float* bf = (const float*)d_in[7];
    const float* Wu = (const float*)d_in[8];
    const float* bu = (const float*)d_in[9];
    const float* Wr = (const float*)d_in[10];
    const float* br = (const float*)d_in[11];
    const float* Wc = (const float*)d_in[12];
    const float* bc = (const float*)d_in[13];
    float* out = (float*)d_out;

    float* ws     = (float*)d_ws;
    float* qW     = ws + 10240;
    float* logits = ws + 337920;
    float* scores = ws + 1157120;

    prep_kernel<<<20, 256, 0, stream>>>(W1, ws);
    qw_kernel<<<1280, 256, 0, stream>>>(targets, b1, ws, qW);
    mlp_kernel<<<3200, 256, 0, stream>>>(gru, targets, W1, W2, b2, Wf, bf, ws, logits);
    softmax_kernel<<<200, 256, 0, stream>>>(logits, scores);
    augru_kernel<<<1024, 256, 0, stream>>>(gru, scores, Wu, bu, Wr, br, Wc, bc, out);
}

// Round 3
// 1108.296 us; speedup vs baseline: 1.1938x; 1.1938x over previous
//
#include <hip/hip_runtime.h>
#include <hip/hip_bf16.h>
#include <math.h>

#define BB 4096
#define TT 200
#define EE 64

// ws float layout:
//  [0,5120)          WkC = W1[64:128]-W1[128:192]   (64x80)
//  [5120,10240)      WqC = W1[0:64]+W1[128:192]     (64x80)
//  [10240,337920)    qW  = targets@WqC + b1         (B x 80)
//  [337920,1157120)  logits [T][B]
//  [1157120,1976320) scoresT [B][T]   (transposed for the recurrence's s_loads)

__device__ __forceinline__ float lane_bcast(float v, int l) {
    return __int_as_float(__builtin_amdgcn_readlane(__float_as_int(v), l));
}

__global__ __launch_bounds__(256) void prep_kernel(const float* __restrict__ W1,
                                                   float* __restrict__ ws) {
    int idx = blockIdx.x * 256 + threadIdx.x;   // i*80+j, i<64
    if (idx >= 64 * 80) return;
    float wa = W1[idx];
    float wb = W1[64 * 80 + idx];
    float wc = W1[128 * 80 + idx];
    ws[idx]        = wb - wc;   // WkC
    ws[5120 + idx] = wa + wc;   // WqC
}

__global__ __launch_bounds__(256) void qw_kernel(const float* __restrict__ targets,
                                                 const float* __restrict__ b1,
                                                 const float* __restrict__ ws,
                                                 float* __restrict__ qW) {
    int idx = blockIdx.x * 256 + threadIdx.x;   // b*80+j
    int b = idx / 80;
    int j = idx - b * 80;
    const float* q  = targets + (size_t)b * 64;
    const float* Wq = ws + 5120;
    float s = b1[j];
#pragma unroll
    for (int i = 0; i < 64; i++) s = fmaf(q[i], Wq[i * 80 + j], s);
    qW[idx] = s;
}

// one thread per (b,t): logit via restructured MLP (R1 LDS-broadcast form)
__global__ __launch_bounds__(256) void mlp_kernel(
    const float* __restrict__ gru, const float* __restrict__ targets,
    const float* __restrict__ W1, const float* __restrict__ W2,
    const float* __restrict__ b2, const float* __restrict__ Wf,
    const float* __restrict__ bf, const float* __restrict__ ws,
    float* __restrict__ logits) {
    __shared__ float4 sWk[1280];   // [64][20 quads]
    __shared__ float4 sWp[1280];
    const float4* WkC = (const float4*)ws;              // 5120 floats
    const float4* Wp  = (const float4*)(W1 + 192 * 80); // last 64 rows of W1
    for (int i = threadIdx.x; i < 1280; i += 256) {
        sWk[i] = WkC[i];
        sWp[i] = Wp[i];
    }
    __syncthreads();

    int idx = blockIdx.x * 256 + threadIdx.x;   // exactly B*T threads
    int b = idx / 200;
    int t = idx - b * 200;
    const float4* kp  = (const float4*)(gru + ((size_t)b * 200 + t) * 64);
    const float4* qp  = (const float4*)(targets + (size_t)b * 64);
    const float4* qWv = (const float4*)(ws + 10240 + (size_t)b * 80);

    float4 h1[20];
#pragma unroll
    for (int j = 0; j < 20; j++) h1[j] = qWv[j];

    for (int i4 = 0; i4 < 16; i4++) {
        float4 kv = kp[i4];
        float4 qv = qp[i4];
        float kk[4] = {kv.x, kv.y, kv.z, kv.w};
        float pp[4] = {qv.x * kv.x, qv.y * kv.y, qv.z * kv.z, qv.w * kv.w};
#pragma unroll
        for (int u = 0; u < 4; u++) {
            const float4* wk = &sWk[(i4 * 4 + u) * 20];
            const float4* wp = &sWp[(i4 * 4 + u) * 20];
            float ki = kk[u], pi = pp[u];
#pragma unroll
            for (int j = 0; j < 20; j++) {
                float4 a = wk[j], c = wp[j];
                h1[j].x = fmaf(ki, a.x, fmaf(pi, c.x, h1[j].x));
                h1[j].y = fmaf(ki, a.y, fmaf(pi, c.y, h1[j].y));
                h1[j].z = fmaf(ki, a.z, fmaf(pi, c.z, h1[j].z));
                h1[j].w = fmaf(ki, a.w, fmaf(pi, c.w, h1[j].w));
            }
        }
    }
    // layer 2: 80 -> 40
    float4 h2[10];
    const float4* b2v = (const float4*)b2;
    const float4* W2v = (const float4*)W2;   // [80][10 quads]
#pragma unroll
    for (int j = 0; j < 10; j++) h2[j] = b2v[j];
#pragma unroll
    for (int iq = 0; iq < 20; iq++) {
        float4 hv = h1[iq];
        float hs[4] = {hv.x, hv.y, hv.z, hv.w};
#pragma unroll
        for (int u = 0; u < 4; u++) {
            float v = hs[u];
            const float4* wr = W2v + (iq * 4 + u) * 10;
#pragma unroll
            for (int j = 0; j < 10; j++) {
                float4 w = wr[j];
                h2[j].x = fmaf(v, w.x, h2[j].x);
                h2[j].y = fmaf(v, w.y, h2[j].y);
                h2[j].z = fmaf(v, w.z, h2[j].z);
                h2[j].w = fmaf(v, w.w, h2[j].w);
            }
        }
    }
    // final: 40 -> 1
    const float4* Wfv = (const float4*)Wf;
    float lg = bf[0];
#pragma unroll
    for (int j = 0; j < 10; j++) {
        float4 w = Wfv[j];
        lg = fmaf(h2[j].x, w.x, lg);
        lg = fmaf(h2[j].y, w.y, lg);
        lg = fmaf(h2[j].z, w.z, lg);
        lg = fmaf(h2[j].w, w.w, lg);
    }
    if (lg == 0.0f) lg = -INFINITY;
    logits[(size_t)t * BB + b] = lg;
}

// softmax over batch dim for each t; writes transposed scores [B][T]
__global__ __launch_bounds__(256) void softmax_kernel(const float* __restrict__ logits,
                                                      float* __restrict__ scoresT) {
    int t = blockIdx.x;
    int tid = threadIdx.x;
    const float* L = logits + (size_t)t * BB;
    float v[16];
#pragma unroll
    for (int i = 0; i < 16; i++) {
        float x = L[tid + i * 256];
        v[i] = (x == 0.0f) ? -INFINITY : x;
    }
    float m = v[0];
#pragma unroll
    for (int i = 1; i < 16; i++) m = fmaxf(m, v[i]);
#pragma unroll
    for (int off = 32; off; off >>= 1) m = fmaxf(m, __shfl_xor(m, off));
    __shared__ float sm[4];
    __shared__ float ss[4];
    int wid = tid >> 6;
    if ((tid & 63) == 0) sm[wid] = m;
    __syncthreads();
    m = fmaxf(fmaxf(sm[0], sm[1]), fmaxf(sm[2], sm[3]));
    float e[16];
    float s = 0.0f;
#pragma unroll
    for (int i = 0; i < 16; i++) {
        e[i] = __expf(v[i] - m);
        s += e[i];
    }
#pragma unroll
    for (int off = 32; off; off >>= 1) s += __shfl_xor(s, off);
    if ((tid & 63) == 0) ss[wid] = s;
    __syncthreads();
    s = ss[0] + ss[1] + ss[2] + ss[3];
    float inv = 1.0f / s;
#pragma unroll
    for (int i = 0; i < 16; i++)
        scoresT[(size_t)(tid + i * 256) * TT + t] = e[i] * inv;
}

// AUGRU: ONE WAVE PER BLOCK, one block per batch row. lane j owns h[j] and
// column j of Wc (128 floats, register-resident: 1-wave block + minwaves=2
// caps VGPR at 256 so the allocator can settle at ~3 waves/SIMD w/o spill).
// x values enter via wave-uniform s_loads (b = blockIdx is uniform);
// r is factored out of the matvec (r scalar per b).
__global__ __launch_bounds__(64, 2) void augru_kernel(
    const float* __restrict__ gru, const float* __restrict__ scoresT,
    const float* __restrict__ Wu, const float* __restrict__ bu,
    const float* __restrict__ Wr, const float* __restrict__ br,
    const float* __restrict__ Wc, const float* __restrict__ bc,
    float* __restrict__ out) {
    int lane = threadIdx.x;       // 0..63
    int b = blockIdx.x;           // wave-uniform by construction

    float wc1[64], wc2[64];
#pragma unroll
    for (int k = 0; k < 64; k++) {
        wc1[k] = Wc[k * 64 + lane];          // xi part, column `lane`
        wc2[k] = Wc[(64 + k) * 64 + lane];   // h*r part
    }
    float wu1l = Wu[lane], wu2l = Wu[64 + lane];
    float wr1l = Wr[lane], wr2l = Wr[64 + lane];
    float bcl = bc[lane];
    float sbu = bu[0], sbr = br[0];

    const float* xrow = gru + (size_t)b * TT * 64;   // uniform base
    const float* scb  = scoresT + (size_t)b * TT;    // uniform base
    float h = 0.0f;
    for (int t = 0; t < TT; t++) {
        float xl = xrow[lane];                        // per-lane (gate partial)
        float sc = scb[t];                            // uniform -> s_load
        float pu = fmaf(xl, wu1l, h * wu2l);
        float pr = fmaf(xl, wr1l, h * wr2l);
#pragma unroll
        for (int off = 32; off; off >>= 1) {
            pu += __shfl_xor(pu, off);
            pr += __shfl_xor(pr, off);
        }
        float u = sc / (1.0f + __expf(-(pu + sbu)));
        float r = 1.0f / (1.0f + __expf(-(pr + sbr)));

        float ax0 = bcl, ax1 = 0.0f, ax2 = 0.0f, ax3 = 0.0f;
        float ah0 = 0.0f, ah1 = 0.0f, ah2 = 0.0f, ah3 = 0.0f;
#pragma unroll
        for (int k = 0; k < 16; k++) {
            float x0 = xrow[4 * k + 0];   // uniform -> s_load
            float x1 = xrow[4 * k + 1];
            float x2 = xrow[4 * k + 2];
            float x3 = xrow[4 * k + 3];
            ax0 = fmaf(x0, wc1[4 * k + 0], ax0);
            ax1 = fmaf(x1, wc1[4 * k + 1], ax1);
            ax2 = fmaf(x2, wc1[4 * k + 2], ax2);
            ax3 = fmaf(x3, wc1[4 * k + 3], ax3);
            float h0 = lane_bcast(h, 4 * k + 0);
            float h1 = lane_bcast(h, 4 * k + 1);
            float h2 = lane_bcast(h, 4 * k + 2);
            float h3 = lane_bcast(h, 4 * k + 3);
            ah0 = fmaf(h0, wc2[4 * k + 0], ah0);
            ah1 = fmaf(h1, wc2[4 * k + 1], ah1);
            ah2 = fmaf(h2, wc2[4 * k + 2], ah2);
            ah3 = fmaf(h3, wc2[4 * k + 3], ah3);
        }
        float arg = ((ax0 + ax1) + (ax2 + ax3)) + r * ((ah0 + ah1) + (ah2 + ah3));
        float ex = __expf(2.0f * arg);                // tanh
        float th = 1.0f - 2.0f / (ex + 1.0f);
        h = fmaf(u, th - h, h);
        xrow += 64;
    }
    out[(size_t)b * 64 + lane] = h;
}

extern "C" void kernel_launch(void* const* d_in, const int* in_sizes, int n_in,
                              void* d_out, int out_size, void* d_ws, size_t ws_size,
                              hipStream_t stream) {
    const float* gru     = (const float*)d_in[0];
    const float* targets = (const float*)d_in[1];
    const float* W1 = (const float*)d_in[2];
    const float* b1 = (const float*)d_in[3];
    const float* W2 = (const float*)d_in[4];
    const float* b2 = (const float*)d_in[5];
    const float* Wf = (const float*)d_in[6];
    const float* bf = (const float*)d_in[7];
    const float* Wu = (const float*)d_in[8];
    const float* bu = (const float*)d_in[9];
    const float* Wr = (const float*)d_in[10];
    const float* br = (const float*)d_in[11];
    const float* Wc = (const float*)d_in[12];
    const float* bc = (const float*)d_in[13];
    float* out = (float*)d_out;

    float* ws      = (float*)d_ws;
    float* logits  = ws + 337920;
    float* scoresT = ws + 1157120;

    prep_kernel<<<20, 256, 0, stream>>>(W1, ws);
    qw_kernel<<<1280, 256, 0, stream>>>(targets, b1, ws, ws + 10240);
    mlp_kernel<<<3200, 256, 0, stream>>>(gru, targets, W1, W2, b2, Wf, bf, ws, logits);
    softmax_kernel<<<200, 256, 0, stream>>>(logits, scoresT);
    augru_kernel<<<4096, 64, 0, stream>>>(gru, scoresT, Wu, bu, Wr, br, Wc, bc, out);
}

// Round 4
// 1078.134 us; speedup vs baseline: 1.2272x; 1.0280x over previous
//
#include <hip/hip_runtime.h>
#include <hip/hip_bf16.h>
#include <math.h>

#define BB 4096
#define TT 200
#define EE 64

// ws float layout:
//  [0,5120)          WkC = W1[64:128]-W1[128:192]   (64x80)
//  [5120,10240)      WqC = W1[0:64]+W1[128:192]     (64x80)
//  [10240,337920)    qW  = targets@WqC + b1         (B x 80)
//  [337920,1157120)  logits [T][B]
//  [1157120,1976320) scores [T][B]

__device__ __forceinline__ float lane_bcast(float v, int l) {
    return __int_as_float(__builtin_amdgcn_readlane(__float_as_int(v), l));
}

__global__ __launch_bounds__(256) void prep_kernel(const float* __restrict__ W1,
                                                   float* __restrict__ ws) {
    int idx = blockIdx.x * 256 + threadIdx.x;   // i*80+j, i<64
    if (idx >= 64 * 80) return;
    float wa = W1[idx];
    float wb = W1[64 * 80 + idx];
    float wc = W1[128 * 80 + idx];
    ws[idx]        = wb - wc;   // WkC
    ws[5120 + idx] = wa + wc;   // WqC
}

__global__ __launch_bounds__(256) void qw_kernel(const float* __restrict__ targets,
                                                 const float* __restrict__ b1,
                                                 const float* __restrict__ ws,
                                                 float* __restrict__ qW) {
    int idx = blockIdx.x * 256 + threadIdx.x;   // b*80+j
    int b = idx / 80;
    int j = idx - b * 80;
    const float* q  = targets + (size_t)b * 64;
    const float* Wq = ws + 5120;
    float s = b1[j];
#pragma unroll
    for (int i = 0; i < 64; i++) s = fmaf(q[i], Wq[i * 80 + j], s);
    qW[idx] = s;
}

// one thread per (b,t): logit via restructured MLP (LDS-broadcast weights)
__global__ __launch_bounds__(256) void mlp_kernel(
    const float* __restrict__ gru, const float* __restrict__ targets,
    const float* __restrict__ W1, const float* __restrict__ W2,
    const float* __restrict__ b2, const float* __restrict__ Wf,
    const float* __restrict__ bf, const float* __restrict__ ws,
    float* __restrict__ logits) {
    __shared__ float4 sWk[1280];   // [64][20 quads]
    __shared__ float4 sWp[1280];
    const float4* WkC = (const float4*)ws;              // 5120 floats
    const float4* Wp  = (const float4*)(W1 + 192 * 80); // last 64 rows of W1
    for (int i = threadIdx.x; i < 1280; i += 256) {
        sWk[i] = WkC[i];
        sWp[i] = Wp[i];
    }
    __syncthreads();

    int idx = blockIdx.x * 256 + threadIdx.x;   // exactly B*T threads
    int b = idx / 200;
    int t = idx - b * 200;
    const float4* kp  = (const float4*)(gru + ((size_t)b * 200 + t) * 64);
    const float4* qp  = (const float4*)(targets + (size_t)b * 64);
    const float4* qWv = (const float4*)(ws + 10240 + (size_t)b * 80);

    float4 h1[20];
#pragma unroll
    for (int j = 0; j < 20; j++) h1[j] = qWv[j];

    for (int i4 = 0; i4 < 16; i4++) {
        float4 kv = kp[i4];
        float4 qv = qp[i4];
        float kk[4] = {kv.x, kv.y, kv.z, kv.w};
        float pp[4] = {qv.x * kv.x, qv.y * kv.y, qv.z * kv.z, qv.w * kv.w};
#pragma unroll
        for (int u = 0; u < 4; u++) {
            const float4* wk = &sWk[(i4 * 4 + u) * 20];
            const float4* wp = &sWp[(i4 * 4 + u) * 20];
            float ki = kk[u], pi = pp[u];
#pragma unroll
            for (int j = 0; j < 20; j++) {
                float4 a = wk[j], c = wp[j];
                h1[j].x = fmaf(ki, a.x, fmaf(pi, c.x, h1[j].x));
                h1[j].y = fmaf(ki, a.y, fmaf(pi, c.y, h1[j].y));
                h1[j].z = fmaf(ki, a.z, fmaf(pi, c.z, h1[j].z));
                h1[j].w = fmaf(ki, a.w, fmaf(pi, c.w, h1[j].w));
            }
        }
    }
    // layer 2: 80 -> 40
    float4 h2[10];
    const float4* b2v = (const float4*)b2;
    const float4* W2v = (const float4*)W2;   // [80][10 quads]
#pragma unroll
    for (int j = 0; j < 10; j++) h2[j] = b2v[j];
#pragma unroll
    for (int iq = 0; iq < 20; iq++) {
        float4 hv = h1[iq];
        float hs[4] = {hv.x, hv.y, hv.z, hv.w};
#pragma unroll
        for (int u = 0; u < 4; u++) {
            float v = hs[u];
            const float4* wr = W2v + (iq * 4 + u) * 10;
#pragma unroll
            for (int j = 0; j < 10; j++) {
                float4 w = wr[j];
                h2[j].x = fmaf(v, w.x, h2[j].x);
                h2[j].y = fmaf(v, w.y, h2[j].y);
                h2[j].z = fmaf(v, w.z, h2[j].z);
                h2[j].w = fmaf(v, w.w, h2[j].w);
            }
        }
    }
    // final: 40 -> 1
    const float4* Wfv = (const float4*)Wf;
    float lg = bf[0];
#pragma unroll
    for (int j = 0; j < 10; j++) {
        float4 w = Wfv[j];
        lg = fmaf(h2[j].x, w.x, lg);
        lg = fmaf(h2[j].y, w.y, lg);
        lg = fmaf(h2[j].z, w.z, lg);
        lg = fmaf(h2[j].w, w.w, lg);
    }
    if (lg == 0.0f) lg = -INFINITY;
    logits[(size_t)t * BB + b] = lg;
}

// softmax over batch dim for each t; scores stored [T][B] (coalesced)
__global__ __launch_bounds__(256) void softmax_kernel(const float* __restrict__ logits,
                                                      float* __restrict__ scores) {
    int t = blockIdx.x;
    int tid = threadIdx.x;
    const float* L = logits + (size_t)t * BB;
    float v[16];
#pragma unroll
    for (int i = 0; i < 16; i++) {
        float x = L[tid + i * 256];
        v[i] = (x == 0.0f) ? -INFINITY : x;
    }
    float m = v[0];
#pragma unroll
    for (int i = 1; i < 16; i++) m = fmaxf(m, v[i]);
#pragma unroll
    for (int off = 32; off; off >>= 1) m = fmaxf(m, __shfl_xor(m, off));
    __shared__ float sm[4];
    __shared__ float ss[4];
    int wid = tid >> 6;
    if ((tid & 63) == 0) sm[wid] = m;
    __syncthreads();
    m = fmaxf(fmaxf(sm[0], sm[1]), fmaxf(sm[2], sm[3]));
    float e[16];
    float s = 0.0f;
#pragma unroll
    for (int i = 0; i < 16; i++) {
        e[i] = __expf(v[i] - m);
        s += e[i];
    }
#pragma unroll
    for (int off = 32; off; off >>= 1) s += __shfl_xor(s, off);
    if ((tid & 63) == 0) ss[wid] = s;
    __syncthreads();
    s = ss[0] + ss[1] + ss[2] + ss[3];
    float inv = 1.0f / s;
    float* S = scores + (size_t)t * BB;
#pragma unroll
    for (int i = 0; i < 16; i++) S[tid + i * 256] = e[i] * inv;
}

// AUGRU, producer/consumer wave specialization. One block (2 waves) per b.
// Wave 0: holds Wc1 columns (64 regs), computes xc_t = x_t@Wc1 + bc and the
//   gate x-dots one step AHEAD of the consumer, into double-buffered LDS.
//   x_t loaded as per-lane coalesced vector dword (no SMEM stall chain).
// Wave 1: holds Wc2 columns (64 regs), computes gates (h-dots via butterfly
//   + x-dots from LDS), candidate = xc + r*(h@Wc2), and the h update.
// Each wave needs ~64 weight regs + temps => no 128-value register demand.
__global__ __launch_bounds__(128, 4) void augru_kernel(
    const float* __restrict__ gru, const float* __restrict__ scores,
    const float* __restrict__ Wu, const float* __restrict__ bu,
    const float* __restrict__ Wr, const float* __restrict__ br,
    const float* __restrict__ Wc, const float* __restrict__ bc,
    float* __restrict__ out) {
    __shared__ float sxc[2][64];
    __shared__ float sxg[2][2];
    const int lane = threadIdx.x & 63;
    const int wid  = threadIdx.x >> 6;
    const int b    = blockIdx.x;
    const float* xrow = gru + (size_t)b * TT * 64;

    if (wid == 0) {
        // ---- producer wave ----
        float wc1[64];
#pragma unroll
        for (int k = 0; k < 64; k++) wc1[k] = Wc[k * 64 + lane];
        float wu1l = Wu[lane], wr1l = Wr[lane];
        float bcl = bc[lane];

        auto produce = [&](int tp, float xl) {
            float pu = xl * wu1l;
            float pr = xl * wr1l;
#pragma unroll
            for (int off = 32; off; off >>= 1) {
                pu += __shfl_xor(pu, off);
                pr += __shfl_xor(pr, off);
            }
            float a0 = bcl, a1 = 0.0f, a2 = 0.0f, a3 = 0.0f;
#pragma unroll
            for (int k = 0; k < 16; k++) {
                a0 = fmaf(lane_bcast(xl, 4 * k + 0), wc1[4 * k + 0], a0);
                a1 = fmaf(lane_bcast(xl, 4 * k + 1), wc1[4 * k + 1], a1);
                a2 = fmaf(lane_bcast(xl, 4 * k + 2), wc1[4 * k + 2], a2);
                a3 = fmaf(lane_bcast(xl, 4 * k + 3), wc1[4 * k + 3], a3);
            }
            int p = tp & 1;
            sxc[p][lane] = (a0 + a1) + (a2 + a3);
            if (lane == 0) sxg[p][0] = pu;
            if (lane == 1) sxg[p][1] = pr;
        };

        float xl = xrow[lane];          // t=0
        float xn = xrow[64 + lane];     // t=1
        produce(0, xl);
        xl = xn;
        __syncthreads();
        for (int t = 0; t < TT; t++) {
            if (t + 1 < TT) {
                float xnn = (t + 2 < TT) ? xrow[(size_t)(t + 2) * 64 + lane] : 0.0f;
                produce(t + 1, xl);
                xl = xnn;
            }
            __syncthreads();
        }
    } else {
        // ---- consumer wave ----
        float wc2[64];
#pragma unroll
        for (int k = 0; k < 64; k++) wc2[k] = Wc[(64 + k) * 64 + lane];
        float wu2l = Wu[64 + lane], wr2l = Wr[64 + lane];
        float sbu = bu[0], sbr = br[0];
        float h = 0.0f;
        __syncthreads();
        for (int t = 0; t < TT; t++) {
            int p = t & 1;
            float sc = scores[(size_t)t * BB + b];   // uniform -> s_load
            float xc = sxc[p][lane];
            float xu = sxg[p][0];
            float xv = sxg[p][1];
            float pu = h * wu2l;
            float pr = h * wr2l;
#pragma unroll
            for (int off = 32; off; off >>= 1) {
                pu += __shfl_xor(pu, off);
                pr += __shfl_xor(pr, off);
            }
            float u = sc / (1.0f + __expf(-(pu + xu + sbu)));
            float r = 1.0f / (1.0f + __expf(-(pr + xv + sbr)));
            float a0 = 0.0f, a1 = 0.0f, a2 = 0.0f, a3 = 0.0f;
#pragma unroll
            for (int k = 0; k < 16; k++) {
                a0 = fmaf(lane_bcast(h, 4 * k + 0), wc2[4 * k + 0], a0);
                a1 = fmaf(lane_bcast(h, 4 * k + 1), wc2[4 * k + 1], a1);
                a2 = fmaf(lane_bcast(h, 4 * k + 2), wc2[4 * k + 2], a2);
                a3 = fmaf(lane_bcast(h, 4 * k + 3), wc2[4 * k + 3], a3);
            }
            float arg = xc + r * ((a0 + a1) + (a2 + a3));
            float ex = __expf(2.0f * arg);           // tanh
            float th = 1.0f - 2.0f / (ex + 1.0f);
            h = fmaf(u, th - h, h);
            __syncthreads();
        }
        out[(size_t)b * 64 + lane] = h;
    }
}

extern "C" void kernel_launch(void* const* d_in, const int* in_sizes, int n_in,
                              void* d_out, int out_size, void* d_ws, size_t ws_size,
                              hipStream_t stream) {
    const float* gru     = (const float*)d_in[0];
    const float* targets = (const float*)d_in[1];
    const float* W1 = (const float*)d_in[2];
    const float* b1 = (const float*)d_in[3];
    const float* W2 = (const float*)d_in[4];
    const float* b2 = (const float*)d_in[5];
    const float* Wf = (const float*)d_in[6];
    const float* bf = (const float*)d_in[7];
    const float* Wu = (const float*)d_in[8];
    const float* bu = (const float*)d_in[9];
    const float* Wr = (const float*)d_in[10];
    const float* br = (const float*)d_in[11];
    const float* Wc = (const float*)d_in[12];
    const float* bc = (const float*)d_in[13];
    float* out = (float*)d_out;

    float* ws     = (float*)d_ws;
    float* logits = ws + 337920;
    float* scores = ws + 1157120;

    prep_kernel<<<20, 256, 0, stream>>>(W1, ws);
    qw_kernel<<<1280, 256, 0, stream>>>(targets, b1, ws, ws + 10240);
    mlp_kernel<<<3200, 256, 0, stream>>>(gru, targets, W1, W2, b2, Wf, bf, ws, logits);
    softmax_kernel<<<200, 256, 0, stream>>>(logits, scores);
    augru_kernel<<<4096, 128, 0, stream>>>(gru, scores, Wu, bu, Wr, br, Wc, bc, out);
}